// Round 17
// baseline (133.507 us; speedup 1.0000x reference)
//
#include <hip/hip_runtime.h>
#include <hip/hip_bf16.h>
#include <cstdint>
#include <cstddef>

typedef unsigned short u16;
typedef __attribute__((ext_vector_type(8))) short bf16x8;
typedef __attribute__((ext_vector_type(4))) float f32x4;

constexpr int Bn = 4;
constexpr int Nq = 8192;
constexpr int Mk = 2048;
constexpr int C1c = 128;
constexpr int C2c = 256;
constexpr int H1c = 256;
constexpr int H2c = 128;

__device__ __forceinline__ float bf2f(u16 u) {
    union { uint32_t i; float f; } v;
    v.i = (uint32_t)u << 16;
    return v.f;
}
__device__ __forceinline__ u16 f2bf(float f) {
    const uint32_t x = __float_as_uint(f);
    return (u16)((x + 0x7FFFu + ((x >> 16) & 1u)) >> 16);
}
__device__ __forceinline__ uint32_t cvtpk(float lo, float hi) {
    uint32_t r;
    asm("v_cvt_pk_bf16_f32 %0, %1, %2" : "=v"(r) : "v"(lo), "v"(hi));
    return r;
}

// ================= K1: knn (scalar-broadcast) + cvt W + gemm1-MFMA (direct KF) =================
// [0,512) knn (64 q/block-wave, 4-way candidate split) | [512,640) cvt W1/W2 | [640,1152) gemm1
__global__ __launch_bounds__(256) void knn_prep_kernel(
    const float* __restrict__ W1, const float* __restrict__ W2,
    u16* __restrict__ W1b, u16* __restrict__ W2b,
    const float* __restrict__ KF, u16* __restrict__ Ptb,
    const float* __restrict__ unknown, const float* __restrict__ known,
    int* __restrict__ idx_out, float* __restrict__ w_out)
{
    __shared__ __align__(16) char smem[32768];
    const int bid = blockIdx.x;
    const int t = threadIdx.x;

    if (bid < 512) {
        // ---- 3-NN: lane = query, candidates via wave-uniform scalar loads ----
        const int b = bid >> 7;                 // 128 blocks per batch
        const int qbase = (bid & 127) * 64;
        const int l = t & 63;                   // query lane
        const int w = t >> 6;                   // wave = candidate quarter
        const int q = qbase + l;

        const float* u = unknown + ((size_t)b * Nq + q) * 3;
        const float ux = u[0], uy = u[1], uz = u[2];
        const float nux = -2.0f * ux, nuy = -2.0f * uy, nuz = -2.0f * uz;

        // track d' = |k|^2 - 2 u.k (ordering identical to true squared distance)
        float d0 = 1e30f, d1 = 1e30f, d2 = 1e30f;
        int i0 = 0, i1 = 0, i2 = 0;

        auto ins = [&](float d, int i) {
            const bool c0 = d < d0, c1 = d < d1, c2 = d < d2;
            const float nd0 = fminf(d0, d);
            const float nd1 = __builtin_amdgcn_fmed3f(d0, d, d1);
            const float nd2 = __builtin_amdgcn_fmed3f(d1, d, d2);
            i2 = c1 ? i1 : (c2 ? i : i2);
            i1 = c0 ? i0 : (c1 ? i : i1);
            i0 = c0 ? i : i0;
            d0 = nd0; d1 = nd1; d2 = nd2;
        };

        const float* kb = known + (size_t)b * Mk * 3;
        const int mbase = w * 512;
        #pragma unroll 4
        for (int mi = 0; mi < 512; ++mi) {
            const int m = mbase + mi;
            // wave-uniform candidate -> scalar loads (no LDS, no per-lane VMEM)
            const float sx = kb[m * 3 + 0];
            const float sy = kb[m * 3 + 1];
            const float sz = kb[m * 3 + 2];
            const float kk = fmaf(sx, sx, fmaf(sy, sy, sz * sz));   // same formula as before
            const float d = fmaf(nux, sx, fmaf(nuy, sy, fmaf(nuz, sz, kk)));
            if (__any(d < d2)) ins(d, m);   // vote-skip when no lane improves
        }

        // ---- merge 4 quarter-triples via LDS ----
        float* dW = (float*)smem;               // [4][64][4] floats = 4096 B
        int* iW = (int*)(smem + 4096);          // [4][64][4] ints  = 4096 B
        const int base4 = (w * 64 + l) * 4;
        dW[base4 + 0] = d0; dW[base4 + 1] = d1; dW[base4 + 2] = d2;
        iW[base4 + 0] = i0; iW[base4 + 1] = i1; iW[base4 + 2] = i2;
        __syncthreads();

        if (t < 64) {
            float D0 = dW[t * 4 + 0], D1 = dW[t * 4 + 1], D2 = dW[t * 4 + 2];
            int I0 = iW[t * 4 + 0], I1 = iW[t * 4 + 1], I2 = iW[t * 4 + 2];
            auto mins = [&](float d, int i) {           // full insert
                const bool c0 = d < D0, c1 = d < D1, c2 = d < D2;
                const float nd0 = fminf(D0, d);
                const float nd1 = __builtin_amdgcn_fmed3f(D0, d, D1);
                const float nd2 = __builtin_amdgcn_fmed3f(D1, d, D2);
                I2 = c1 ? I1 : (c2 ? i : I2);
                I1 = c0 ? I0 : (c1 ? i : I1);
                I0 = c0 ? i : I0;
                D0 = nd0; D1 = nd1; D2 = nd2;
            };
            auto mins_hi = [&](float d, int i) {        // d >= new D0 (partner sorted)
                const bool c1 = d < D1, c2 = d < D2;
                const float nd1 = fminf(D1, d);
                const float nd2 = __builtin_amdgcn_fmed3f(D1, d, D2);
                I2 = c1 ? I1 : (c2 ? i : I2);
                I1 = c1 ? i : I1;
                D1 = nd1; D2 = nd2;
            };
            auto mins_top = [&](float d, int i) {       // d >= new D1
                const bool c2 = d < D2;
                D2 = fminf(D2, d);
                I2 = c2 ? i : I2;
            };
            #pragma unroll
            for (int ww = 1; ww < 4; ++ww) {
                const int pb = (ww * 64 + t) * 4;
                mins(dW[pb + 0], iW[pb + 0]);
                mins_hi(dW[pb + 1], iW[pb + 1]);
                mins_top(dW[pb + 2], iW[pb + 2]);
            }
            const float* uq = unknown + ((size_t)b * Nq + qbase + t) * 3;
            const float qx = uq[0], qy = uq[1], qz = uq[2];
            const float uu = fmaf(qx, qx, fmaf(qy, qy, qz * qz));
            const float f0 = D0 + uu, f1 = D1 + uu, f2 = D2 + uu;
            const float r0 = 1.0f / (f0 + 1e-8f);
            const float r1 = 1.0f / (f1 + 1e-8f);
            const float r2 = 1.0f / (f2 + 1e-8f);
            const float inv = 1.0f / (r0 + r1 + r2);
            const size_t obase = ((size_t)b * Nq + qbase + t) * 3;
            idx_out[obase + 0] = I0;
            idx_out[obase + 1] = I1;
            idx_out[obase + 2] = I2;
            w_out[obase + 0] = r0 * inv;
            w_out[obase + 1] = r1 * inv;
            w_out[obase + 2] = r2 * inv;
        }
    } else if (bid < 640) {
        const int cb = bid - 512;
        const float* X = (cb < 96) ? W1 : W2;
        u16* Y = (cb < 96) ? W1b : W2b;
        const int i = ((cb < 96) ? cb : (cb - 96)) * 256 + t;
        const float4 v = *(const float4*)&X[(size_t)i * 4];
        ushort4 o;
        o.x = f2bf(v.x); o.y = f2bf(v.y); o.z = f2bf(v.z); o.w = f2bf(v.w);
        *(ushort4*)&Y[(size_t)i * 4] = o;
    } else {
        // ---- gemm1 MFMA: Ptb[b][m][h] = sum_c f2bf(KF[b][c][m]) * f2bf(W1[h][c]) ----
        u16* As = (u16*)smem;            // [64][40] u16
        u16* Bs = (u16*)(smem + 5120);   // [64][40] u16
        const int f = bid - 640;
        const int b = f >> 7;
        const int rem = f & 127;
        const int m0 = (rem >> 2) * 64;
        const int h0 = (rem & 3) * 64;
        const float* KFb = KF + (size_t)b * C2c * Mk;
        const int l = t & 63, wv = t >> 6;
        const int wr = wv >> 1, wc = wv & 1;

        f32x4 acc[2][2];
        const f32x4 z = {0.0f, 0.0f, 0.0f, 0.0f};
        acc[0][0] = z; acc[0][1] = z; acc[1][0] = z; acc[1][1] = z;

        const int cA = t >> 3;
        const int mcA = (t & 7) * 8;
        const int hB = t >> 2;
        const int khB = (t & 3) * 8;

        for (int kt = 0; kt < 8; ++kt) {
            const int kc = kt * 32;
            {
                const float* src = &KFb[(size_t)(kc + cA) * Mk + m0 + mcA];
                const float4 v0 = *(const float4*)&src[0];
                const float4 v1 = *(const float4*)&src[4];
                As[(mcA + 0) * 40 + cA] = f2bf(v0.x);
                As[(mcA + 1) * 40 + cA] = f2bf(v0.y);
                As[(mcA + 2) * 40 + cA] = f2bf(v0.z);
                As[(mcA + 3) * 40 + cA] = f2bf(v0.w);
                As[(mcA + 4) * 40 + cA] = f2bf(v1.x);
                As[(mcA + 5) * 40 + cA] = f2bf(v1.y);
                As[(mcA + 6) * 40 + cA] = f2bf(v1.z);
                As[(mcA + 7) * 40 + cA] = f2bf(v1.w);
            }
            {
                const float* src = &W1[(size_t)(h0 + hB) * 384 + kc + khB];
                const float4 v0 = *(const float4*)&src[0];
                const float4 v1 = *(const float4*)&src[4];
                u16 o[8] = {f2bf(v0.x), f2bf(v0.y), f2bf(v0.z), f2bf(v0.w),
                            f2bf(v1.x), f2bf(v1.y), f2bf(v1.z), f2bf(v1.w)};
                *(uint4*)&Bs[hB * 40 + khB] = *(const uint4*)o;
            }
            __syncthreads();
            bf16x8 af[2], bf[2];
            #pragma unroll
            for (int ff = 0; ff < 2; ++ff) {
                af[ff] = *(const bf16x8*)&As[(wr * 32 + ff * 16 + (l & 15)) * 40 + (l >> 4) * 8];
                bf[ff] = *(const bf16x8*)&Bs[(wc * 32 + ff * 16 + (l & 15)) * 40 + (l >> 4) * 8];
            }
            #pragma unroll
            for (int i = 0; i < 2; ++i)
                #pragma unroll
                for (int j = 0; j < 2; ++j)
                    acc[i][j] = __builtin_amdgcn_mfma_f32_16x16x32_bf16(af[i], bf[j], acc[i][j], 0, 0, 0);
            __syncthreads();
        }

        u16* Pb = Ptb + (size_t)b * Mk * 256;
        const int cb = l & 15, rg = (l >> 4) * 4;
        #pragma unroll
        for (int i = 0; i < 2; ++i) {
            #pragma unroll
            for (int r = 0; r < 4; ++r) {
                const int row = m0 + wr * 32 + i * 16 + rg + r;
                #pragma unroll
                for (int j = 0; j < 2; ++j)
                    Pb[(size_t)row * 256 + h0 + wc * 32 + j * 16 + cb] = f2bf(acc[i][j][r]);
            }
        }
    }
}

// ================= gemm2: A from f32 UF via XOR-swizzled LDS transpose (r16 proven) =================
__global__ __launch_bounds__(256) void mfma_gemm2(
    const float* __restrict__ UF,         // (B, 128, Nq) f32
    const u16* __restrict__ Bt,           // W1b + 256 (row stride 384)
    u16* __restrict__ Cout,               // y1b (B, Nq, 256)
    const u16* __restrict__ Ptb,
    const int* __restrict__ idx, const float* __restrict__ wgt,
    float* __restrict__ partS, float* __restrict__ partQ)
{
    __shared__ __align__(16) char smem[16384];
    __shared__ float redS[4][128], redQ[4][128];
    u16* As = (u16*)smem;
    u16* Bs = (u16*)(smem + 8192);
    float (*Ytmp)[128] = (float(*)[128])smem;

    const int b = blockIdx.z;
    const int m0 = blockIdx.x * 128, n0 = blockIdx.y * 128;
    const int t = threadIdx.x;
    const int l = t & 63, wv = t >> 6;
    const int wr = wv >> 1, wc = wv & 1;

    const float* UFb = UF + (size_t)b * C1c * Nq;
    const int p = t & 15;
    const int qg = t >> 4;
    const int rB0 = t >> 2, rB1v = (t + 256) >> 2;
    const int koB = (t & 3) * 8;

    f32x4 acc[4][4];
    const f32x4 z = {0.0f, 0.0f, 0.0f, 0.0f};
    #pragma unroll
    for (int i = 0; i < 4; ++i)
        #pragma unroll
        for (int j = 0; j < 4; ++j) acc[i][j] = z;

    float4 va0, va1, vb0, vb1;
    {
        const float* r0 = &UFb[(size_t)(2 * p) * Nq + m0 + qg * 8];
        const float* r1 = r0 + Nq;
        va0 = *(const float4*)&r0[0];
        va1 = *(const float4*)&r0[4];
        vb0 = *(const float4*)&r1[0];
        vb1 = *(const float4*)&r1[4];
    }
    uint4 b0 = *(const uint4*)&Bt[(size_t)(n0 + rB0) * 384 + koB];
    uint4 b1 = *(const uint4*)&Bt[(size_t)(n0 + rB1v) * 384 + koB];

    for (int kt = 0; kt < C1c / 32; ++kt) {
        {
            const float* la = (const float*)&va0;
            const float* lb = (const float*)&va1;
            const float* ha = (const float*)&vb0;
            const float* hb = (const float*)&vb1;
            #pragma unroll
            for (int i = 0; i < 8; ++i) {
                const int row = qg * 8 + i;
                const float lo = (i < 4) ? la[i] : lb[i - 4];
                const float hi = (i < 4) ? ha[i] : hb[i - 4];
                const int byte = row * 64 + ((((p >> 2) ^ (row & 3)) << 4)) + (p & 3) * 4;
                *(uint32_t*)((char*)As + byte) = cvtpk(lo, hi);
            }
        }
        *(uint4*)&Bs[(size_t)rB0 * 32 + koB] = b0;
        *(uint4*)&Bs[(size_t)rB1v * 32 + koB] = b1;
        __syncthreads();
        if (kt + 1 < C1c / 32) {
            const int k0 = (kt + 1) * 32;
            const float* r0 = &UFb[(size_t)(k0 + 2 * p) * Nq + m0 + qg * 8];
            const float* r1 = r0 + Nq;
            va0 = *(const float4*)&r0[0];
            va1 = *(const float4*)&r0[4];
            vb0 = *(const float4*)&r1[0];
            vb1 = *(const float4*)&r1[4];
            b0 = *(const uint4*)&Bt[(size_t)(n0 + rB0) * 384 + k0 + koB];
            b1 = *(const uint4*)&Bt[(size_t)(n0 + rB1v) * 384 + k0 + koB];
        }
        bf16x8 af[4], bf[4];
        #pragma unroll
        for (int f = 0; f < 4; ++f) {
            const int row = wr * 64 + f * 16 + (l & 15);
            af[f] = *(const bf16x8*)((char*)As + row * 64 + ((((l >> 4) ^ (l & 3)) << 4)));
            bf[f] = *(const bf16x8*)&Bs[(wc * 64 + f * 16 + (l & 15)) * 32 + (l >> 4) * 8];
        }
        #pragma unroll
        for (int i = 0; i < 4; ++i)
            #pragma unroll
            for (int j = 0; j < 4; ++j)
                acc[i][j] = __builtin_amdgcn_mfma_f32_16x16x32_bf16(af[i], bf[j], acc[i][j], 0, 0, 0);
        __syncthreads();
    }

    const int cb = l & 15;
    const int rg = (l >> 4) * 4;
    const int colblk = t & 15;
    const int rowblk = t >> 4;
    float s8[8] = {0, 0, 0, 0, 0, 0, 0, 0}, q8[8] = {0, 0, 0, 0, 0, 0, 0, 0};
    const u16* Pb = Ptb + (size_t)b * Mk * 256;

    for (int q = 0; q < 4; ++q) {
        __syncthreads();
        if (wr == (q >> 1)) {
            #pragma unroll
            for (int ii = 0; ii < 2; ++ii) {
                const int i = (q & 1) * 2 + ii;
                #pragma unroll
                for (int r = 0; r < 4; ++r) {
                    const int Rq = ii * 16 + rg + r;
                    #pragma unroll
                    for (int j = 0; j < 4; ++j)
                        Ytmp[Rq][wc * 64 + j * 16 + cb] = acc[i][j][r];
                }
            }
        }
        __syncthreads();
        #pragma unroll
        for (int rr = 0; rr < 2; ++rr) {
            const int Rq = rowblk * 2 + rr;
            const int R = m0 + q * 32 + Rq;
            const size_t ib = ((size_t)b * Nq + R) * 3;
            const int j0 = idx[ib], j1 = idx[ib + 1], j2 = idx[ib + 2];
            const float w0 = wgt[ib], w1 = wgt[ib + 1], w2 = wgt[ib + 2];
            const int c8 = colblk * 8;
            const int Cc0 = n0 + c8;
            const float* yrow = &Ytmp[Rq][c8];
            const float4 y0 = *(const float4*)&yrow[0];
            const float4 y1v = *(const float4*)&yrow[4];
            const uint4 p0 = *(const uint4*)&Pb[(size_t)j0 * 256 + Cc0];
            const uint4 p1 = *(const uint4*)&Pb[(size_t)j1 * 256 + Cc0];
            const uint4 p2 = *(const uint4*)&Pb[(size_t)j2 * 256 + Cc0];
            const u16* pp0 = (const u16*)&p0;
            const u16* pp1 = (const u16*)&p1;
            const u16* pp2 = (const u16*)&p2;
            const float* ya = (const float*)&y0;
            const float* yb = (const float*)&y1v;
            float v[8];
            #pragma unroll
            for (int c = 0; c < 8; ++c) {
                const float a = (c < 4) ? ya[c] : yb[c - 4];
                const float vv = a + w0 * bf2f(pp0[c]) + w1 * bf2f(pp1[c]) + w2 * bf2f(pp2[c]);
                v[c] = vv;
                s8[c] += vv;
                q8[c] += vv * vv;
            }
            uint4 o;
            uint32_t* po = (uint32_t*)&o;
            po[0] = cvtpk(v[0], v[1]);
            po[1] = cvtpk(v[2], v[3]);
            po[2] = cvtpk(v[4], v[5]);
            po[3] = cvtpk(v[6], v[7]);
            *(uint4*)&Cout[(size_t)b * Nq * 256 + (size_t)R * 256 + Cc0] = o;
        }
    }

    #pragma unroll
    for (int c = 0; c < 8; ++c) {
        s8[c] += __shfl_xor(s8[c], 16);
        s8[c] += __shfl_xor(s8[c], 32);
        q8[c] += __shfl_xor(q8[c], 16);
        q8[c] += __shfl_xor(q8[c], 32);
    }
    if (l < 16) {
        #pragma unroll
        for (int c = 0; c < 8; ++c) {
            redS[wv][l * 8 + c] = s8[c];
            redQ[wv][l * 8 + c] = q8[c];
        }
    }
    __syncthreads();
    if (t < 128) {
        const float S = redS[0][t] + redS[1][t] + redS[2][t] + redS[3][t];
        const float Q = redQ[0][t] + redQ[1][t] + redQ[2][t] + redQ[3][t];
        const int pblk = blockIdx.z * gridDim.x + blockIdx.x;
        partS[(size_t)pblk * 256 + blockIdx.y * 128 + t] = S;
        partQ[(size_t)pblk * 256 + blockIdx.y * 128 + t] = Q;
    }
}

// ---------------- BN1 finalize: 16 blocks x 16 channels (r13 proven) ----------------
__global__ __launch_bounds__(256) void bn1_finalize_mb(
    const float* __restrict__ pS, const float* __restrict__ pQ,
    const float* __restrict__ g, const float* __restrict__ beta,
    float* __restrict__ scale, float* __restrict__ bias)
{
    __shared__ float rs[256], rq[256];
    const int cc = threadIdx.x & 15;
    const int sl = threadIdx.x >> 4;
    const int ch = blockIdx.x * 16 + cc;
    float s = 0.0f, q = 0.0f;
    for (int i = sl; i < 256; i += 16) {
        s += pS[(size_t)i * 256 + ch];
        q += pQ[(size_t)i * 256 + ch];
    }
    rs[threadIdx.x] = s;
    rq[threadIdx.x] = q;
    __syncthreads();
    if (sl == 0) {
        for (int k = 1; k < 16; ++k) {
            s += rs[k * 16 + cc];
            q += rq[k * 16 + cc];
        }
        const float cnt = (float)(Bn * Nq);
        const float mean = s / cnt;
        const float var = q / cnt - mean * mean;
        const float rv = rsqrtf(var + 1e-5f);
        const float sc = g[ch] * rv;
        scale[ch] = sc;
        bias[ch] = beta[ch] - mean * sc;
    }
}

// ---------------- BN transform for staged B-operand (8 bf16), cvt_pk packed ----------------
__device__ __forceinline__ uint4 bnx(uint4 x, const float* scs, const float* bis, int k) {
    const u16* p = (const u16*)&x;
    const float4 s0 = *(const float4*)&scs[k];
    const float4 s1 = *(const float4*)&scs[k + 4];
    const float4 b0 = *(const float4*)&bis[k];
    const float4 b1 = *(const float4*)&bis[k + 4];
    const float* sa = (const float*)&s0;
    const float* sb = (const float*)&s1;
    const float* ba = (const float*)&b0;
    const float* bb = (const float*)&b1;
    uint4 o;
    uint32_t* po = (uint32_t*)&o;
    #pragma unroll
    for (int w2 = 0; w2 < 2; ++w2) {
        const float a0 = fmaxf(0.0f, fmaf(bf2f(p[2 * w2 + 0]), sa[2 * w2 + 0], ba[2 * w2 + 0]));
        const float a1 = fmaxf(0.0f, fmaf(bf2f(p[2 * w2 + 1]), sa[2 * w2 + 1], ba[2 * w2 + 1]));
        po[w2] = cvtpk(a0, a1);
    }
    #pragma unroll
    for (int w2 = 0; w2 < 2; ++w2) {
        const float a0 = fmaxf(0.0f, fmaf(bf2f(p[4 + 2 * w2 + 0]), sb[2 * w2 + 0], bb[2 * w2 + 0]));
        const float a1 = fmaxf(0.0f, fmaf(bf2f(p[4 + 2 * w2 + 1]), sb[2 * w2 + 1], bb[2 * w2 + 1]));
        po[2 + w2] = cvtpk(a0, a1);
    }
    return o;
}

// ================= gemm3: 64x128 tile, BNIN + row stats; bf16 y2b out (r14 proven) =================
__global__ __launch_bounds__(256) void mfma_gemm3(
    const u16* __restrict__ W2b,
    const u16* __restrict__ Y,
    u16* __restrict__ y2b,
    const float* __restrict__ bn_s, const float* __restrict__ bn_b,
    float* __restrict__ partS, float* __restrict__ partQ)
{
    __shared__ u16 As[2048];
    __shared__ u16 Bs[4096];
    __shared__ float scs[256], bis[256];
    __shared__ float sS[2][64], sQ[2][64];

    const int b = blockIdx.z;
    const int m0 = blockIdx.x * 64;
    const int n0 = blockIdx.y * 128;
    const int t = threadIdx.x;
    const int l = t & 63, wv = t >> 6;
    const int wr = wv >> 1, wc = wv & 1;

    scs[t] = bn_s[t];
    bis[t] = bn_b[t];

    const u16* Yb = Y + (size_t)b * Nq * 256;
    const int rA = t >> 2;
    const int rB1 = (t + 256) >> 2;
    const int ko = (t & 3) * 8;

    f32x4 acc[2][4];
    const f32x4 z = {0.0f, 0.0f, 0.0f, 0.0f};
    #pragma unroll
    for (int i = 0; i < 2; ++i)
        #pragma unroll
        for (int j = 0; j < 4; ++j) acc[i][j] = z;

    uint4 a0 = *(const uint4*)&W2b[(size_t)(m0 + rA) * 256 + ko];
    uint4 b0 = *(const uint4*)&Yb[(size_t)(n0 + rA) * 256 + ko];
    uint4 b1 = *(const uint4*)&Yb[(size_t)(n0 + rB1) * 256 + ko];
    __syncthreads();

    for (int kt = 0; kt < 8; ++kt) {
        const int k = kt * 32 + ko;
        *(uint4*)&As[t * 8] = a0;
        *(uint4*)&Bs[t * 8] = bnx(b0, scs, bis, k);
        *(uint4*)&Bs[(t + 256) * 8] = bnx(b1, scs, bis, k);
        __syncthreads();
        if (kt + 1 < 8) {
            const int k0 = (kt + 1) * 32;
            a0 = *(const uint4*)&W2b[(size_t)(m0 + rA) * 256 + k0 + ko];
            b0 = *(const uint4*)&Yb[(size_t)(n0 + rA) * 256 + k0 + ko];
            b1 = *(const uint4*)&Yb[(size_t)(n0 + rB1) * 256 + k0 + ko];
        }
        bf16x8 af[2], bf[4];
        #pragma unroll
        for (int f = 0; f < 2; ++f)
            af[f] = *(const bf16x8*)&As[(wr * 32 + f * 16 + (l & 15)) * 32 + (l >> 4) * 8];
        #pragma unroll
        for (int f = 0; f < 4; ++f)
            bf[f] = *(const bf16x8*)&Bs[(wc * 64 + f * 16 + (l & 15)) * 32 + (l >> 4) * 8];
        #pragma unroll
        for (int i = 0; i < 2; ++i)
            #pragma unroll
            for (int j = 0; j < 4; ++j)
                acc[i][j] = __builtin_amdgcn_mfma_f32_16x16x32_bf16(af[i], bf[j], acc[i][j], 0, 0, 0);
        __syncthreads();
    }

    const int cb = l & 15;
    const int rg = (l >> 4) * 4;
    u16* ob = y2b + (size_t)b * H2c * Nq;
    #pragma unroll
    for (int i = 0; i < 2; ++i) {
        #pragma unroll
        for (int r = 0; r < 4; ++r) {
            const int Rl = wr * 32 + i * 16 + rg + r;
            #pragma unroll
            for (int j = 0; j < 4; ++j) {
                const int Cc = n0 + wc * 64 + j * 16 + cb;
                ob[(size_t)(m0 + Rl) * Nq + Cc] = f2bf(acc[i][j][r]);
            }
            float s = acc[i][0][r] + acc[i][1][r] + acc[i][2][r] + acc[i][3][r];
            float q = acc[i][0][r] * acc[i][0][r] + acc[i][1][r] * acc[i][1][r] +
                      acc[i][2][r] * acc[i][2][r] + acc[i][3][r] * acc[i][3][r];
            s += __shfl_xor(s, 1); s += __shfl_xor(s, 2);
            s += __shfl_xor(s, 4); s += __shfl_xor(s, 8);
            q += __shfl_xor(q, 1); q += __shfl_xor(q, 2);
            q += __shfl_xor(q, 4); q += __shfl_xor(q, 8);
            if ((l & 15) == 0) {
                sS[wc][Rl] = s;
                sQ[wc][Rl] = q;
            }
        }
    }
    __syncthreads();
    if (t < 64) {
        const float S = sS[0][t] + sS[1][t];
        const float Q = sQ[0][t] + sQ[1][t];
        const int p = blockIdx.z * gridDim.y + blockIdx.y;
        partS[(size_t)p * 128 + m0 + t] = S;
        partQ[(size_t)p * 128 + m0 + t] = Q;
    }
}

// ---------------- BN2 finalize: 8 blocks x 16 channels (r14 proven) ----------------
__global__ __launch_bounds__(256) void bn2_finalize_mb(
    const float* __restrict__ pS, const float* __restrict__ pQ,
    const float* __restrict__ g, const float* __restrict__ beta,
    float* __restrict__ scale, float* __restrict__ bias)
{
    __shared__ float rs[256], rq[256];
    const int cc = threadIdx.x & 15;
    const int sl = threadIdx.x >> 4;
    const int ch = blockIdx.x * 16 + cc;
    float s = 0.0f, q = 0.0f;
    for (int i = sl; i < 256; i += 16) {
        s += pS[(size_t)i * 128 + ch];
        q += pQ[(size_t)i * 128 + ch];
    }
    rs[threadIdx.x] = s;
    rq[threadIdx.x] = q;
    __syncthreads();
    if (sl == 0) {
        for (int k = 1; k < 16; ++k) {
            s += rs[k * 16 + cc];
            q += rq[k * 16 + cc];
        }
        const float cnt = (float)(Bn * Nq);
        const float mean = s / cnt;
        const float var = q / cnt - mean * mean;
        const float rv = rsqrtf(var + 1e-5f);
        const float sc = g[ch] * rv;
        scale[ch] = sc;
        bias[ch] = beta[ch] - mean * sc;
    }
}

// ---------------- BN2 apply: y2b bf16 -> out f32 (r14 proven) ----------------
__global__ __launch_bounds__(256) void bn2_apply_simple(
    const u16* __restrict__ y2b, float* __restrict__ out,
    const float* __restrict__ scale, const float* __restrict__ bias)
{
    const size_t base = (size_t)blockIdx.x * 2048;
    const int c = (int)((base / Nq) % H2c);
    const float sc = scale[c], bi = bias[c];
    const size_t i = base + threadIdx.x * 8;
    const uint4 v = *(const uint4*)&y2b[i];
    const u16* pv = (const u16*)&v;
    float4 o0, o1;
    o0.x = fmaxf(0.0f, fmaf(bf2f(pv[0]), sc, bi));
    o0.y = fmaxf(0.0f, fmaf(bf2f(pv[1]), sc, bi));
    o0.z = fmaxf(0.0f, fmaf(bf2f(pv[2]), sc, bi));
    o0.w = fmaxf(0.0f, fmaf(bf2f(pv[3]), sc, bi));
    o1.x = fmaxf(0.0f, fmaf(bf2f(pv[4]), sc, bi));
    o1.y = fmaxf(0.0f, fmaf(bf2f(pv[5]), sc, bi));
    o1.z = fmaxf(0.0f, fmaf(bf2f(pv[6]), sc, bi));
    o1.w = fmaxf(0.0f, fmaf(bf2f(pv[7]), sc, bi));
    *(float4*)&out[i] = o0;
    *(float4*)&out[i + 4] = o1;
}

extern "C" void kernel_launch(void* const* d_in, const int* in_sizes, int n_in,
                              void* d_out, int out_size, void* d_ws, size_t ws_size,
                              hipStream_t stream) {
    const float* unknown = (const float*)d_in[0];
    const float* known = (const float*)d_in[1];
    const float* unknow_feats = (const float*)d_in[2];
    const float* known_feats = (const float*)d_in[3];
    const float* W1 = (const float*)d_in[4];
    const float* g1 = (const float*)d_in[5];
    const float* b1 = (const float*)d_in[6];
    const float* W2 = (const float*)d_in[7];
    const float* g2 = (const float*)d_in[8];
    const float* b2 = (const float*)d_in[9];
    float* out = (float*)d_out;

    char* w = (char*)d_ws;
    u16* W1b = (u16*)w; w += (size_t)H1c * 384 * 2;
    u16* W2b = (u16*)w; w += (size_t)H2c * H1c * 2;
    u16* Ptb = (u16*)w; w += (size_t)Bn * Mk * H1c * 2;
    u16* y1b = (u16*)w; w += (size_t)Bn * Nq * H1c * 2;
    u16* y2b = (u16*)w; w += (size_t)Bn * H2c * Nq * 2;
    int* idx = (int*)w; w += (size_t)Bn * Nq * 3 * 4;
    float* wgt = (float*)w; w += (size_t)Bn * Nq * 3 * 4;
    float* pS1 = (float*)w; w += (size_t)256 * 256 * 4;
    float* pQ1 = (float*)w; w += (size_t)256 * 256 * 4;
    float* pS2 = (float*)w; w += (size_t)256 * 128 * 4;
    float* pQ2 = (float*)w; w += (size_t)256 * 128 * 4;
    float* scale1 = (float*)w; w += 1024;
    float* bias1 = (float*)w; w += 1024;
    float* scale2 = (float*)w; w += 1024;
    float* bias2 = (float*)w; w += 1024;

    // 1) K1: knn (scalar-broadcast) + weight cvt + gemm1-MFMA
    knn_prep_kernel<<<1152, 256, 0, stream>>>(W1, W2, W1b, W2b,
                                              known_feats, Ptb,
                                              unknown, known, idx, wgt);

    // 2) gemm2: y1b = UF(direct) @ W1[:,256:]^T + gather(Ptb)  [+ BN1 partials]
    mfma_gemm2<<<dim3(Nq / 128, H1c / 128, Bn), 256, 0, stream>>>(
        unknow_feats, W1b + C2c, y1b, Ptb, idx, wgt, pS1, pQ1);

    // 3) BN1 finalize -> scale1/bias1 (16 blocks)
    bn1_finalize_mb<<<16, 256, 0, stream>>>(pS1, pQ1, g1, b1, scale1, bias1);

    // 4) gemm3: y2b (bf16) = W2 @ relu(bn1(y1b))^T  [+ BN2 partials]
    mfma_gemm3<<<dim3(2, Nq / 128, Bn), 256, 0, stream>>>(
        W2b, y1b, y2b, scale1, bias1, pS2, pQ2);

    // 5) BN2 finalize -> scale2/bias2 (8 blocks)
    bn2_finalize_mb<<<8, 256, 0, stream>>>(pS2, pQ2, g2, b2, scale2, bias2);

    // 6) BN2 apply: y2b -> out
    bn2_apply_simple<<<(Bn * H2c * Nq) / 2048, 256, 0, stream>>>(y2b, out, scale2, bias2);
}

// Round 18
// 91.071 us; speedup vs baseline: 1.4660x; 1.4660x over previous
//
#include <hip/hip_runtime.h>
#include <hip/hip_bf16.h>
#include <cstdint>
#include <cstddef>

typedef unsigned short u16;
typedef __attribute__((ext_vector_type(8))) short bf16x8;
typedef __attribute__((ext_vector_type(4))) float f32x4;

constexpr int Bn = 4;
constexpr int Nq = 8192;
constexpr int Mk = 2048;
constexpr int C1c = 128;
constexpr int C2c = 256;
constexpr int H1c = 256;
constexpr int H2c = 128;

__device__ __forceinline__ float bf2f(u16 u) {
    union { uint32_t i; float f; } v;
    v.i = (uint32_t)u << 16;
    return v.f;
}
__device__ __forceinline__ u16 f2bf(float f) {
    const uint32_t x = __float_as_uint(f);
    return (u16)((x + 0x7FFFu + ((x >> 16) & 1u)) >> 16);
}
__device__ __forceinline__ uint32_t cvtpk(float lo, float hi) {
    uint32_t r;
    asm("v_cvt_pk_bf16_f32 %0, %1, %2" : "=v"(r) : "v"(lo), "v"(hi));
    return r;
}

// ================= K1: knn + cvt W + gemm1-MFMA (direct KF) + UF transpose (r14 proven best) =================
// [0,1024) knn | [1024,1152) cvt W1/W2 | [1152,1664) gemm1 | [1664,2688) UF transpose
__global__ __launch_bounds__(256) void knn_prep_kernel(
    const float* __restrict__ W1, const float* __restrict__ W2,
    u16* __restrict__ W1b, u16* __restrict__ W2b,
    const float* __restrict__ KF, u16* __restrict__ Ptb,
    const float* __restrict__ UF, u16* __restrict__ UFt,
    const float* __restrict__ unknown, const float* __restrict__ known,
    int* __restrict__ idx_out, float* __restrict__ w_out)
{
    __shared__ __align__(16) char smem[32768];
    const int bid = blockIdx.x;
    const int t = threadIdx.x;

    if (bid < 1024) {
        float4* kp = (float4*)smem;
        const int b = bid >> 8;
        const int n0 = (bid & 255) * 32;

        const float* kb = known + (size_t)b * Mk * 3;
        for (int i = t; i < Mk; i += 256) {
            const float x = kb[i * 3 + 0], y = kb[i * 3 + 1], z = kb[i * 3 + 2];
            kp[i] = make_float4(x, y, z, fmaf(x, x, fmaf(y, y, z * z)));
        }
        __syncthreads();

        const int q = n0 + (t >> 3);
        const int s = t & 7;
        const float* u = unknown + ((size_t)b * Nq + q) * 3;
        const float ux = u[0], uy = u[1], uz = u[2];
        const float nux = -2.0f * ux, nuy = -2.0f * uy, nuz = -2.0f * uz;
        const float uu = fmaf(ux, ux, fmaf(uy, uy, uz * uz));

        float d0 = 1e30f, d1 = 1e30f, d2 = 1e30f;
        int i0 = 0, i1 = 0, i2 = 0;

        auto ins = [&](float d, int i) {
            const bool c0 = d < d0, c1 = d < d1, c2 = d < d2;
            const float nd0 = fminf(d0, d);
            const float nd1 = __builtin_amdgcn_fmed3f(d0, d, d1);
            const float nd2 = __builtin_amdgcn_fmed3f(d1, d, d2);
            i2 = c1 ? i1 : (c2 ? i : i2);
            i1 = c0 ? i0 : (c1 ? i : i1);
            i0 = c0 ? i : i0;
            d0 = nd0; d1 = nd1; d2 = nd2;
        };

        #pragma unroll 8
        for (int it = 0; it < Mk / 8; ++it) {
            const int m = it * 8 + s;
            const float4 p = kp[m];
            const float d = fmaf(nux, p.x, fmaf(nuy, p.y, fmaf(nuz, p.z, p.w)));
            ins(d, m);
        }
        #pragma unroll
        for (int off = 1; off <= 4; off <<= 1) {
            const float e0 = __shfl_xor(d0, off), e1 = __shfl_xor(d1, off), e2 = __shfl_xor(d2, off);
            const int j0 = __shfl_xor(i0, off), j1 = __shfl_xor(i1, off), j2 = __shfl_xor(i2, off);
            ins(e0, j0);
            ins(e1, j1);
            ins(e2, j2);
        }
        if (s == 0) {
            const float f0 = d0 + uu, f1 = d1 + uu, f2 = d2 + uu;
            const float r0 = 1.0f / (f0 + 1e-8f);
            const float r1 = 1.0f / (f1 + 1e-8f);
            const float r2 = 1.0f / (f2 + 1e-8f);
            const float inv = 1.0f / (r0 + r1 + r2);
            const size_t base = ((size_t)b * Nq + q) * 3;
            idx_out[base + 0] = i0;
            idx_out[base + 1] = i1;
            idx_out[base + 2] = i2;
            w_out[base + 0] = r0 * inv;
            w_out[base + 1] = r1 * inv;
            w_out[base + 2] = r2 * inv;
        }
    } else if (bid < 1152) {
        const int cb = bid - 1024;
        const float* X = (cb < 96) ? W1 : W2;
        u16* Y = (cb < 96) ? W1b : W2b;
        const int i = ((cb < 96) ? cb : (cb - 96)) * 256 + t;
        const float4 v = *(const float4*)&X[(size_t)i * 4];
        ushort4 o;
        o.x = f2bf(v.x); o.y = f2bf(v.y); o.z = f2bf(v.z); o.w = f2bf(v.w);
        *(ushort4*)&Y[(size_t)i * 4] = o;
    } else if (bid < 1664) {
        u16* As = (u16*)smem;
        u16* Bs = (u16*)(smem + 5120);
        const int f = bid - 1152;
        const int b = f >> 7;
        const int rem = f & 127;
        const int m0 = (rem >> 2) * 64;
        const int h0 = (rem & 3) * 64;
        const float* KFb = KF + (size_t)b * C2c * Mk;
        const int l = t & 63, wv = t >> 6;
        const int wr = wv >> 1, wc = wv & 1;

        f32x4 acc[2][2];
        const f32x4 z = {0.0f, 0.0f, 0.0f, 0.0f};
        acc[0][0] = z; acc[0][1] = z; acc[1][0] = z; acc[1][1] = z;

        const int cA = t >> 3;
        const int mcA = (t & 7) * 8;
        const int hB = t >> 2;
        const int khB = (t & 3) * 8;

        for (int kt = 0; kt < 8; ++kt) {
            const int kc = kt * 32;
            {
                const float* src = &KFb[(size_t)(kc + cA) * Mk + m0 + mcA];
                const float4 v0 = *(const float4*)&src[0];
                const float4 v1 = *(const float4*)&src[4];
                As[(mcA + 0) * 40 + cA] = f2bf(v0.x);
                As[(mcA + 1) * 40 + cA] = f2bf(v0.y);
                As[(mcA + 2) * 40 + cA] = f2bf(v0.z);
                As[(mcA + 3) * 40 + cA] = f2bf(v0.w);
                As[(mcA + 4) * 40 + cA] = f2bf(v1.x);
                As[(mcA + 5) * 40 + cA] = f2bf(v1.y);
                As[(mcA + 6) * 40 + cA] = f2bf(v1.z);
                As[(mcA + 7) * 40 + cA] = f2bf(v1.w);
            }
            {
                const float* src = &W1[(size_t)(h0 + hB) * 384 + kc + khB];
                const float4 v0 = *(const float4*)&src[0];
                const float4 v1 = *(const float4*)&src[4];
                u16 o[8] = {f2bf(v0.x), f2bf(v0.y), f2bf(v0.z), f2bf(v0.w),
                            f2bf(v1.x), f2bf(v1.y), f2bf(v1.z), f2bf(v1.w)};
                *(uint4*)&Bs[hB * 40 + khB] = *(const uint4*)o;
            }
            __syncthreads();
            bf16x8 af[2], bf[2];
            #pragma unroll
            for (int ff = 0; ff < 2; ++ff) {
                af[ff] = *(const bf16x8*)&As[(wr * 32 + ff * 16 + (l & 15)) * 40 + (l >> 4) * 8];
                bf[ff] = *(const bf16x8*)&Bs[(wc * 32 + ff * 16 + (l & 15)) * 40 + (l >> 4) * 8];
            }
            #pragma unroll
            for (int i = 0; i < 2; ++i)
                #pragma unroll
                for (int j = 0; j < 2; ++j)
                    acc[i][j] = __builtin_amdgcn_mfma_f32_16x16x32_bf16(af[i], bf[j], acc[i][j], 0, 0, 0);
            __syncthreads();
        }

        u16* Pb = Ptb + (size_t)b * Mk * 256;
        const int cb = l & 15, rg = (l >> 4) * 4;
        #pragma unroll
        for (int i = 0; i < 2; ++i) {
            #pragma unroll
            for (int r = 0; r < 4; ++r) {
                const int row = m0 + wr * 32 + i * 16 + rg + r;
                #pragma unroll
                for (int j = 0; j < 2; ++j)
                    Pb[(size_t)row * 256 + h0 + wc * 32 + j * 16 + cb] = f2bf(acc[i][j][r]);
            }
        }
    } else {
        const int f = bid - 1664;
        const int b = f >> 8, rem = f & 255;
        const int m0 = (rem >> 1) * 64, c0 = (rem & 1) * 64;
        const float* X = UF + (size_t)b * C1c * Nq;
        u16* Y = UFt + (size_t)b * Nq * C1c;
        float (*T)[65] = (float(*)[65])smem;
        const int m4 = (t & 15) * 4, cr = t >> 4;
        #pragma unroll
        for (int i = 0; i < 4; ++i) {
            const float4 v = *(const float4*)&X[(size_t)(c0 + cr + i * 16) * Nq + m0 + m4];
            T[cr + i * 16][m4 + 0] = v.x;
            T[cr + i * 16][m4 + 1] = v.y;
            T[cr + i * 16][m4 + 2] = v.z;
            T[cr + i * 16][m4 + 3] = v.w;
        }
        __syncthreads();
        const int c4 = (t & 15) * 4, mr = t >> 4;
        #pragma unroll
        for (int i = 0; i < 4; ++i) {
            const int m = mr + i * 16;
            ushort4 o;
            o.x = f2bf(T[c4 + 0][m]);
            o.y = f2bf(T[c4 + 1][m]);
            o.z = f2bf(T[c4 + 2][m]);
            o.w = f2bf(T[c4 + 3][m]);
            *(ushort4*)&Y[(size_t)(m0 + m) * C1c + c0 + c4] = o;
        }
    }
}

// ================= gemm2: 128x128 MFMA + LDS-restaged wide-gather epilogue + BN1 partials =================
__global__ __launch_bounds__(256) void mfma_gemm2(
    const u16* __restrict__ A,            // UFt (B, Nq, 128)
    const u16* __restrict__ Bt,           // W1b + 256 (row stride 384)
    u16* __restrict__ Cout,               // y1b (B, Nq, 256)
    const u16* __restrict__ Ptb,
    const int* __restrict__ idx, const float* __restrict__ wgt,
    float* __restrict__ partS, float* __restrict__ partQ)
{
    __shared__ __align__(16) char smem[16384];
    __shared__ float redS[4][128], redQ[4][128];
    u16* As = (u16*)smem;
    u16* Bs = (u16*)(smem + 8192);
    float (*Ytmp)[128] = (float(*)[128])smem;

    const int b = blockIdx.z;
    const int m0 = blockIdx.x * 128, n0 = blockIdx.y * 128;
    const int t = threadIdx.x;
    const int l = t & 63, wv = t >> 6;
    const int wr = wv >> 1, wc = wv & 1;

    const u16* Ab = A + (size_t)b * Nq * C1c;
    const int rA0 = t >> 2, rA1 = (t + 256) >> 2;
    const int ko = (t & 3) * 8;

    f32x4 acc[4][4];
    const f32x4 z = {0.0f, 0.0f, 0.0f, 0.0f};
    #pragma unroll
    for (int i = 0; i < 4; ++i)
        #pragma unroll
        for (int j = 0; j < 4; ++j) acc[i][j] = z;

    uint4 a0 = *(const uint4*)&Ab[(size_t)(m0 + rA0) * C1c + ko];
    uint4 a1 = *(const uint4*)&Ab[(size_t)(m0 + rA1) * C1c + ko];
    uint4 b0 = *(const uint4*)&Bt[(size_t)(n0 + rA0) * 384 + ko];
    uint4 b1 = *(const uint4*)&Bt[(size_t)(n0 + rA1) * 384 + ko];

    for (int kt = 0; kt < C1c / 32; ++kt) {
        *(uint4*)&As[t * 8] = a0;
        *(uint4*)&As[(t + 256) * 8] = a1;
        *(uint4*)&Bs[t * 8] = b0;
        *(uint4*)&Bs[(t + 256) * 8] = b1;
        __syncthreads();
        if (kt + 1 < C1c / 32) {
            const int k0 = (kt + 1) * 32;
            a0 = *(const uint4*)&Ab[(size_t)(m0 + rA0) * C1c + k0 + ko];
            a1 = *(const uint4*)&Ab[(size_t)(m0 + rA1) * C1c + k0 + ko];
            b0 = *(const uint4*)&Bt[(size_t)(n0 + rA0) * 384 + k0 + ko];
            b1 = *(const uint4*)&Bt[(size_t)(n0 + rA1) * 384 + k0 + ko];
        }
        bf16x8 af[4], bf[4];
        #pragma unroll
        for (int f = 0; f < 4; ++f) {
            af[f] = *(const bf16x8*)&As[(wr * 64 + f * 16 + (l & 15)) * 32 + (l >> 4) * 8];
            bf[f] = *(const bf16x8*)&Bs[(wc * 64 + f * 16 + (l & 15)) * 32 + (l >> 4) * 8];
        }
        #pragma unroll
        for (int i = 0; i < 4; ++i)
            #pragma unroll
            for (int j = 0; j < 4; ++j)
                acc[i][j] = __builtin_amdgcn_mfma_f32_16x16x32_bf16(af[i], bf[j], acc[i][j], 0, 0, 0);
        __syncthreads();
    }

    const int cb = l & 15;
    const int rg = (l >> 4) * 4;
    const int colblk = t & 15;
    const int rowblk = t >> 4;
    float s8[8] = {0, 0, 0, 0, 0, 0, 0, 0}, q8[8] = {0, 0, 0, 0, 0, 0, 0, 0};
    const u16* Pb = Ptb + (size_t)b * Mk * 256;

    for (int q = 0; q < 4; ++q) {
        __syncthreads();
        if (wr == (q >> 1)) {
            #pragma unroll
            for (int ii = 0; ii < 2; ++ii) {
                const int i = (q & 1) * 2 + ii;
                #pragma unroll
                for (int r = 0; r < 4; ++r) {
                    const int Rq = ii * 16 + rg + r;
                    #pragma unroll
                    for (int j = 0; j < 4; ++j)
                        Ytmp[Rq][wc * 64 + j * 16 + cb] = acc[i][j][r];
                }
            }
        }
        __syncthreads();
        #pragma unroll
        for (int rr = 0; rr < 2; ++rr) {
            const int Rq = rowblk * 2 + rr;
            const int R = m0 + q * 32 + Rq;
            const size_t ib = ((size_t)b * Nq + R) * 3;
            const int j0 = idx[ib], j1 = idx[ib + 1], j2 = idx[ib + 2];
            const float w0 = wgt[ib], w1 = wgt[ib + 1], w2 = wgt[ib + 2];
            const int c8 = colblk * 8;
            const int Cc0 = n0 + c8;
            const float* yrow = &Ytmp[Rq][c8];
            const float4 y0 = *(const float4*)&yrow[0];
            const float4 y1v = *(const float4*)&yrow[4];
            const uint4 p0 = *(const uint4*)&Pb[(size_t)j0 * 256 + Cc0];
            const uint4 p1 = *(const uint4*)&Pb[(size_t)j1 * 256 + Cc0];
            const uint4 p2 = *(const uint4*)&Pb[(size_t)j2 * 256 + Cc0];
            const u16* pp0 = (const u16*)&p0;
            const u16* pp1 = (const u16*)&p1;
            const u16* pp2 = (const u16*)&p2;
            const float* ya = (const float*)&y0;
            const float* yb = (const float*)&y1v;
            float v[8];
            #pragma unroll
            for (int c = 0; c < 8; ++c) {
                const float a = (c < 4) ? ya[c] : yb[c - 4];
                const float vv = a + w0 * bf2f(pp0[c]) + w1 * bf2f(pp1[c]) + w2 * bf2f(pp2[c]);
                v[c] = vv;
                s8[c] += vv;
                q8[c] += vv * vv;
            }
            uint4 o;
            uint32_t* po = (uint32_t*)&o;
            po[0] = cvtpk(v[0], v[1]);
            po[1] = cvtpk(v[2], v[3]);
            po[2] = cvtpk(v[4], v[5]);
            po[3] = cvtpk(v[6], v[7]);
            *(uint4*)&Cout[(size_t)b * Nq * 256 + (size_t)R * 256 + Cc0] = o;
        }
    }

    #pragma unroll
    for (int c = 0; c < 8; ++c) {
        s8[c] += __shfl_xor(s8[c], 16);
        s8[c] += __shfl_xor(s8[c], 32);
        q8[c] += __shfl_xor(q8[c], 16);
        q8[c] += __shfl_xor(q8[c], 32);
    }
    if (l < 16) {
        #pragma unroll
        for (int c = 0; c < 8; ++c) {
            redS[wv][l * 8 + c] = s8[c];
            redQ[wv][l * 8 + c] = q8[c];
        }
    }
    __syncthreads();
    if (t < 128) {
        const float S = redS[0][t] + redS[1][t] + redS[2][t] + redS[3][t];
        const float Q = redQ[0][t] + redQ[1][t] + redQ[2][t] + redQ[3][t];
        const int pblk = blockIdx.z * gridDim.x + blockIdx.x;
        partS[(size_t)pblk * 256 + blockIdx.y * 128 + t] = S;
        partQ[(size_t)pblk * 256 + blockIdx.y * 128 + t] = Q;
    }
}

// ---------------- BN1 finalize: 16 blocks x 16 channels ----------------
__global__ __launch_bounds__(256) void bn1_finalize_mb(
    const float* __restrict__ pS, const float* __restrict__ pQ,
    const float* __restrict__ g, const float* __restrict__ beta,
    float* __restrict__ scale, float* __restrict__ bias)
{
    __shared__ float rs[256], rq[256];
    const int cc = threadIdx.x & 15;
    const int sl = threadIdx.x >> 4;
    const int ch = blockIdx.x * 16 + cc;
    float s = 0.0f, q = 0.0f;
    for (int i = sl; i < 256; i += 16) {
        s += pS[(size_t)i * 256 + ch];
        q += pQ[(size_t)i * 256 + ch];
    }
    rs[threadIdx.x] = s;
    rq[threadIdx.x] = q;
    __syncthreads();
    if (sl == 0) {
        for (int k = 1; k < 16; ++k) {
            s += rs[k * 16 + cc];
            q += rq[k * 16 + cc];
        }
        const float cnt = (float)(Bn * Nq);
        const float mean = s / cnt;
        const float var = q / cnt - mean * mean;
        const float rv = rsqrtf(var + 1e-5f);
        const float sc = g[ch] * rv;
        scale[ch] = sc;
        bias[ch] = beta[ch] - mean * sc;
    }
}

// ---------------- BN transform for staged B-operand (8 bf16), cvt_pk packed ----------------
__device__ __forceinline__ uint4 bnx(uint4 x, const float* scs, const float* bis, int k) {
    const u16* p = (const u16*)&x;
    const float4 s0 = *(const float4*)&scs[k];
    const float4 s1 = *(const float4*)&scs[k + 4];
    const float4 b0 = *(const float4*)&bis[k];
    const float4 b1 = *(const float4*)&bis[k + 4];
    const float* sa = (const float*)&s0;
    const float* sb = (const float*)&s1;
    const float* ba = (const float*)&b0;
    const float* bb = (const float*)&b1;
    uint4 o;
    uint32_t* po = (uint32_t*)&o;
    #pragma unroll
    for (int w2 = 0; w2 < 2; ++w2) {
        const float a0 = fmaxf(0.0f, fmaf(bf2f(p[2 * w2 + 0]), sa[2 * w2 + 0], ba[2 * w2 + 0]));
        const float a1 = fmaxf(0.0f, fmaf(bf2f(p[2 * w2 + 1]), sa[2 * w2 + 1], ba[2 * w2 + 1]));
        po[w2] = cvtpk(a0, a1);
    }
    #pragma unroll
    for (int w2 = 0; w2 < 2; ++w2) {
        const float a0 = fmaxf(0.0f, fmaf(bf2f(p[4 + 2 * w2 + 0]), sb[2 * w2 + 0], bb[2 * w2 + 0]));
        const float a1 = fmaxf(0.0f, fmaf(bf2f(p[4 + 2 * w2 + 1]), sb[2 * w2 + 1], bb[2 * w2 + 1]));
        po[2 + w2] = cvtpk(a0, a1);
    }
    return o;
}

// ================= gemm3: 64x128 tile, BNIN + row stats; bf16 y2b out =================
__global__ __launch_bounds__(256) void mfma_gemm3(
    const u16* __restrict__ W2b,
    const u16* __restrict__ Y,
    u16* __restrict__ y2b,
    const float* __restrict__ bn_s, const float* __restrict__ bn_b,
    float* __restrict__ partS, float* __restrict__ partQ)
{
    __shared__ u16 As[2048];
    __shared__ u16 Bs[4096];
    __shared__ float scs[256], bis[256];
    __shared__ float sS[2][64], sQ[2][64];

    const int b = blockIdx.z;
    const int m0 = blockIdx.x * 64;
    const int n0 = blockIdx.y * 128;
    const int t = threadIdx.x;
    const int l = t & 63, wv = t >> 6;
    const int wr = wv >> 1, wc = wv & 1;

    scs[t] = bn_s[t];
    bis[t] = bn_b[t];

    const u16* Yb = Y + (size_t)b * Nq * 256;
    const int rA = t >> 2;
    const int rB1 = (t + 256) >> 2;
    const int ko = (t & 3) * 8;

    f32x4 acc[2][4];
    const f32x4 z = {0.0f, 0.0f, 0.0f, 0.0f};
    #pragma unroll
    for (int i = 0; i < 2; ++i)
        #pragma unroll
        for (int j = 0; j < 4; ++j) acc[i][j] = z;

    uint4 a0 = *(const uint4*)&W2b[(size_t)(m0 + rA) * 256 + ko];
    uint4 b0 = *(const uint4*)&Yb[(size_t)(n0 + rA) * 256 + ko];
    uint4 b1 = *(const uint4*)&Yb[(size_t)(n0 + rB1) * 256 + ko];
    __syncthreads();

    for (int kt = 0; kt < 8; ++kt) {
        const int k = kt * 32 + ko;
        *(uint4*)&As[t * 8] = a0;
        *(uint4*)&Bs[t * 8] = bnx(b0, scs, bis, k);
        *(uint4*)&Bs[(t + 256) * 8] = bnx(b1, scs, bis, k);
        __syncthreads();
        if (kt + 1 < 8) {
            const int k0 = (kt + 1) * 32;
            a0 = *(const uint4*)&W2b[(size_t)(m0 + rA) * 256 + k0 + ko];
            b0 = *(const uint4*)&Yb[(size_t)(n0 + rA) * 256 + k0 + ko];
            b1 = *(const uint4*)&Yb[(size_t)(n0 + rB1) * 256 + k0 + ko];
        }
        bf16x8 af[2], bf[4];
        #pragma unroll
        for (int f = 0; f < 2; ++f)
            af[f] = *(const bf16x8*)&As[(wr * 32 + f * 16 + (l & 15)) * 32 + (l >> 4) * 8];
        #pragma unroll
        for (int f = 0; f < 4; ++f)
            bf[f] = *(const bf16x8*)&Bs[(wc * 64 + f * 16 + (l & 15)) * 32 + (l >> 4) * 8];
        #pragma unroll
        for (int i = 0; i < 2; ++i)
            #pragma unroll
            for (int j = 0; j < 4; ++j)
                acc[i][j] = __builtin_amdgcn_mfma_f32_16x16x32_bf16(af[i], bf[j], acc[i][j], 0, 0, 0);
        __syncthreads();
    }

    const int cb = l & 15;
    const int rg = (l >> 4) * 4;
    u16* ob = y2b + (size_t)b * H2c * Nq;
    #pragma unroll
    for (int i = 0; i < 2; ++i) {
        #pragma unroll
        for (int r = 0; r < 4; ++r) {
            const int Rl = wr * 32 + i * 16 + rg + r;
            #pragma unroll
            for (int j = 0; j < 4; ++j) {
                const int Cc = n0 + wc * 64 + j * 16 + cb;
                ob[(size_t)(m0 + Rl) * Nq + Cc] = f2bf(acc[i][j][r]);
            }
            float s = acc[i][0][r] + acc[i][1][r] + acc[i][2][r] + acc[i][3][r];
            float q = acc[i][0][r] * acc[i][0][r] + acc[i][1][r] * acc[i][1][r] +
                      acc[i][2][r] * acc[i][2][r] + acc[i][3][r] * acc[i][3][r];
            s += __shfl_xor(s, 1); s += __shfl_xor(s, 2);
            s += __shfl_xor(s, 4); s += __shfl_xor(s, 8);
            q += __shfl_xor(q, 1); q += __shfl_xor(q, 2);
            q += __shfl_xor(q, 4); q += __shfl_xor(q, 8);
            if ((l & 15) == 0) {
                sS[wc][Rl] = s;
                sQ[wc][Rl] = q;
            }
        }
    }
    __syncthreads();
    if (t < 64) {
        const float S = sS[0][t] + sS[1][t];
        const float Q = sQ[0][t] + sQ[1][t];
        const int p = blockIdx.z * gridDim.y + blockIdx.y;
        partS[(size_t)p * 128 + m0 + t] = S;
        partQ[(size_t)p * 128 + m0 + t] = Q;
    }
}

// ---------------- BN2 finalize: 8 blocks x 16 channels ----------------
__global__ __launch_bounds__(256) void bn2_finalize_mb(
    const float* __restrict__ pS, const float* __restrict__ pQ,
    const float* __restrict__ g, const float* __restrict__ beta,
    float* __restrict__ scale, float* __restrict__ bias)
{
    __shared__ float rs[256], rq[256];
    const int cc = threadIdx.x & 15;
    const int sl = threadIdx.x >> 4;
    const int ch = blockIdx.x * 16 + cc;
    float s = 0.0f, q = 0.0f;
    for (int i = sl; i < 256; i += 16) {
        s += pS[(size_t)i * 128 + ch];
        q += pQ[(size_t)i * 128 + ch];
    }
    rs[threadIdx.x] = s;
    rq[threadIdx.x] = q;
    __syncthreads();
    if (sl == 0) {
        for (int k = 1; k < 16; ++k) {
            s += rs[k * 16 + cc];
            q += rq[k * 16 + cc];
        }
        const float cnt = (float)(Bn * Nq);
        const float mean = s / cnt;
        const float var = q / cnt - mean * mean;
        const float rv = rsqrtf(var + 1e-5f);
        const float sc = g[ch] * rv;
        scale[ch] = sc;
        bias[ch] = beta[ch] - mean * sc;
    }
}

// ---------------- BN2 apply: y2b bf16 -> out f32 ----------------
__global__ __launch_bounds__(256) void bn2_apply_simple(
    const u16* __restrict__ y2b, float* __restrict__ out,
    const float* __restrict__ scale, const float* __restrict__ bias)
{
    const size_t base = (size_t)blockIdx.x * 2048;
    const int c = (int)((base / Nq) % H2c);
    const float sc = scale[c], bi = bias[c];
    const size_t i = base + threadIdx.x * 8;
    const uint4 v = *(const uint4*)&y2b[i];
    const u16* pv = (const u16*)&v;
    float4 o0, o1;
    o0.x = fmaxf(0.0f, fmaf(bf2f(pv[0]), sc, bi));
    o0.y = fmaxf(0.0f, fmaf(bf2f(pv[1]), sc, bi));
    o0.z = fmaxf(0.0f, fmaf(bf2f(pv[2]), sc, bi));
    o0.w = fmaxf(0.0f, fmaf(bf2f(pv[3]), sc, bi));
    o1.x = fmaxf(0.0f, fmaf(bf2f(pv[4]), sc, bi));
    o1.y = fmaxf(0.0f, fmaf(bf2f(pv[5]), sc, bi));
    o1.z = fmaxf(0.0f, fmaf(bf2f(pv[6]), sc, bi));
    o1.w = fmaxf(0.0f, fmaf(bf2f(pv[7]), sc, bi));
    *(float4*)&out[i] = o0;
    *(float4*)&out[i + 4] = o1;
}

extern "C" void kernel_launch(void* const* d_in, const int* in_sizes, int n_in,
                              void* d_out, int out_size, void* d_ws, size_t ws_size,
                              hipStream_t stream) {
    const float* unknown = (const float*)d_in[0];
    const float* known = (const float*)d_in[1];
    const float* unknow_feats = (const float*)d_in[2];
    const float* known_feats = (const float*)d_in[3];
    const float* W1 = (const float*)d_in[4];
    const float* g1 = (const float*)d_in[5];
    const float* b1 = (const float*)d_in[6];
    const float* W2 = (const float*)d_in[7];
    const float* g2 = (const float*)d_in[8];
    const float* b2 = (const float*)d_in[9];
    float* out = (float*)d_out;

    char* w = (char*)d_ws;
    u16* UFt = (u16*)w; w += (size_t)Bn * Nq * C1c * 2;
    u16* W1b = (u16*)w; w += (size_t)H1c * 384 * 2;
    u16* W2b = (u16*)w; w += (size_t)H2c * H1c * 2;
    u16* Ptb = (u16*)w; w += (size_t)Bn * Mk * H1c * 2;
    u16* y1b = (u16*)w; w += (size_t)Bn * Nq * H1c * 2;
    u16* y2b = (u16*)w; w += (size_t)Bn * H2c * Nq * 2;
    int* idx = (int*)w; w += (size_t)Bn * Nq * 3 * 4;
    float* wgt = (float*)w; w += (size_t)Bn * Nq * 3 * 4;
    float* pS1 = (float*)w; w += (size_t)256 * 256 * 4;
    float* pQ1 = (float*)w; w += (size_t)256 * 256 * 4;
    float* pS2 = (float*)w; w += (size_t)256 * 128 * 4;
    float* pQ2 = (float*)w; w += (size_t)256 * 128 * 4;
    float* scale1 = (float*)w; w += 1024;
    float* bias1 = (float*)w; w += 1024;
    float* scale2 = (float*)w; w += 1024;
    float* bias2 = (float*)w; w += 1024;

    // 1) K1: knn + weight cvt + gemm1-MFMA (direct from KF) + UF transpose
    knn_prep_kernel<<<2688, 256, 0, stream>>>(W1, W2, W1b, W2b,
                                              known_feats, Ptb, unknow_feats, UFt,
                                              unknown, known, idx, wgt);

    // 2) gemm2: y1b = UFt @ W1[:,256:]^T + gather(Ptb)  [+ BN1 partials]
    mfma_gemm2<<<dim3(Nq / 128, H1c / 128, Bn), 256, 0, stream>>>(
        UFt, W1b + C2c, y1b, Ptb, idx, wgt, pS1, pQ1);

    // 3) BN1 finalize -> scale1/bias1 (16 blocks)
    bn1_finalize_mb<<<16, 256, 0, stream>>>(pS1, pQ1, g1, b1, scale1, bias1);

    // 4) gemm3: y2b (bf16) = W2 @ relu(bn1(y1b))^T  [+ BN2 partials]
    mfma_gemm3<<<dim3(2, Nq / 128, Bn), 256, 0, stream>>>(
        W2b, y1b, y2b, scale1, bias1, pS2, pQ2);

    // 5) BN2 finalize -> scale2/bias2 (8 blocks)
    bn2_finalize_mb<<<8, 256, 0, stream>>>(pS2, pQ2, g2, b2, scale2, bias2);

    // 6) BN2 apply: y2b -> out
    bn2_apply_simple<<<(Bn * H2c * Nq) / 2048, 256, 0, stream>>>(y2b, out, scale2, bias2);
}